// Round 1
// 505.623 us; speedup vs baseline: 1.0010x; 1.0010x over previous
//
#include <hip/hip_runtime.h>
#include <hip/hip_bf16.h>
#include <stdint.h>

// MLA fused pipeline, fp32 I/O, bf16 MFMA internals.
// R7: gemm_bt rewritten as 256x256-tile, 512-thread, 8-wave kernel with the
// 8-phase-density counted-vmcnt schedule (guide T2+T3+T4+T5). R6 counters:
// MfmaUtil 27.7 / HBM 25% / conflicts 0 -> m97-structure barrier-drain bound.
// Structure here:
//  - BK=32, ring of 4 LDS tile buffers (A+B = 128 KiB), prefetch 3 tiles
//    ahead via global_load_lds (2 issues per phase).
//  - 2 phases per K-tile: {8 or 4 ds_read_b128 | 2 global_load_lds | barrier |
//    lgkmcnt(0)+sched_barrier | setprio(1) 16xMFMA setprio(0) | barrier}.
//  - vmcnt(8) once per K-tile (never 0 in the loop). Tail prefetches clamp
//    their source tile (never skipped) so per-wave issue counts stay uniform
//    and the vmcnt arithmetic remains exact for every iteration.
//  - XOR chunk swizzle slot = c ^ (row&3) (4x16B chunks per 64B row), inverse
//    permutation applied on the per-lane global source (LDS dest stays
//    lane-contiguous as global_load_lds requires).
//  - bf16 epilogue repacks through LDS -> 512B-contiguous row stores (R6
//    measured WRITE_SIZE 2x ideal from 32B store segments).

typedef __bf16 bf16_t;
typedef __bf16 bf16x8 __attribute__((ext_vector_type(8)));
typedef float f32x4 __attribute__((ext_vector_type(4)));

__device__ __forceinline__ void async_copy16(const void* g, void* l) {
  __builtin_amdgcn_global_load_lds(
      (__attribute__((address_space(1))) void*)(void*)g,
      (__attribute__((address_space(3))) void*)l, 16, 0, 0);
}

// ---------------------------------------------------------------------------
// GEMM: C[M,N](ldc) = A[M,K](lda) @ BT[N,K]^T + bias. bf16 in, OT out.
// 256x256 tile, BK=32 ring-4, 512 threads (8 waves 2Mx4N, 128x64 each).
// M%256==0, N%256==0, K%32==0, K>=96.
// ---------------------------------------------------------------------------
template <typename OT>
__global__ __launch_bounds__(512, 2) void gemm_bt256(
    const bf16_t* __restrict__ A, long lda,
    const bf16_t* __restrict__ BT,
    const float* __restrict__ bias,
    OT* __restrict__ C, long ldc,
    int M, int N, int K)
{
  __shared__ __align__(16) bf16_t As[4][8192];   // [ring][256 rows x 32 k]
  __shared__ __align__(16) bf16_t Bs[4][8192];

  const int tid  = threadIdx.x;
  const int lane = tid & 63;
  const int w    = tid >> 6;
  const int wm   = w >> 2, wn = w & 3;           // wave grid 2 x 4
  const int quad = lane >> 4, r16 = lane & 15;
  const long row0 = (long)blockIdx.y * 256;
  const long col0 = (long)blockIdx.x * 256;
  const int NT = K >> 5;

  // Staging coords: chunk idx = s*512 + tid; row = idx>>2, slot = idx&3,
  // global chunk cg = slot ^ (row&3). (row&3) identical for s=0/1 since
  // the s=1 half starts at row 128.
  const int rr0 = tid >> 2;
  const int cg0 = (((tid & 3) ^ (rr0 & 3)) << 3);

  f32x4 acc[8][4];
#pragma unroll
  for (int i = 0; i < 8; i++)
#pragma unroll
    for (int j = 0; j < 4; j++)
      acc[i][j] = (f32x4){0.f, 0.f, 0.f, 0.f};

  // Prologue: stage tiles 0..2 into ring slots 0..2 (12 issues/wave).
#pragma unroll
  for (int t = 0; t < 3; t++) {
    const long kk = (long)((t < NT) ? t : NT - 1) << 5;
    const long ga = (row0 + rr0) * lda + kk + cg0;
    const long gb = (col0 + rr0) * (long)K + kk + cg0;
    async_copy16(A  + ga,                  &As[t][w * 512]);
    async_copy16(BT + gb,                  &Bs[t][w * 512]);
    async_copy16(A  + ga + 128 * lda,      &As[t][4096 + w * 512]);
    async_copy16(BT + gb + 128 * (long)K,  &Bs[t][4096 + w * 512]);
  }
  // Gate tile 0 (8 younger issues for tiles 1,2 stay in flight).
  asm volatile("s_waitcnt vmcnt(8)" ::: "memory");
  __builtin_amdgcn_s_barrier();

  for (int t = 0; t < NT; t++) {
    const bf16_t* as = &As[t & 3][0];
    const bf16_t* bs = &Bs[t & 3][0];
    bf16_t* pa = &As[(t + 3) & 3][0];    // slot of dead tile t-1
    bf16_t* pb = &Bs[(t + 3) & 3][0];
    const int  pt  = ((t + 3) < NT) ? (t + 3) : NT - 1;   // clamp, never skip
    const long pkk = (long)pt << 5;
    const long ga = (row0 + rr0) * lda + pkk + cg0;
    const long gb = (col0 + rr0) * (long)K + pkk + cg0;

    bf16x8 av[4], bv[4];

    // ---- phase 1: m-frags 0..3 x n-frags 0..3 ----
#pragma unroll
    for (int i = 0; i < 4; i++) {
      const int ra = wm * 128 + i * 16 + r16;
      av[i] = *(const bf16x8*)(as + ra * 32 + ((quad ^ (ra & 3)) << 3));
    }
#pragma unroll
    for (int j = 0; j < 4; j++) {
      const int rb = wn * 64 + j * 16 + r16;
      bv[j] = *(const bf16x8*)(bs + rb * 32 + ((quad ^ (rb & 3)) << 3));
    }
    async_copy16(A  + ga, pa + w * 512);
    async_copy16(BT + gb, pb + w * 512);
    asm volatile("" ::: "memory");
    __builtin_amdgcn_s_barrier();
    asm volatile("s_waitcnt lgkmcnt(0)" ::: "memory");
    __builtin_amdgcn_sched_barrier(0);
    __builtin_amdgcn_s_setprio(1);
#pragma unroll
    for (int i = 0; i < 4; i++)
#pragma unroll
      for (int j = 0; j < 4; j++)
        acc[i][j] = __builtin_amdgcn_mfma_f32_16x16x32_bf16(av[i], bv[j], acc[i][j], 0, 0, 0);
    __builtin_amdgcn_s_setprio(0);
    __builtin_amdgcn_sched_barrier(0);
    asm volatile("" ::: "memory");
    __builtin_amdgcn_s_barrier();

    // ---- phase 2: m-frags 4..7 (bv reused in registers) ----
#pragma unroll
    for (int i = 0; i < 4; i++) {
      const int ra = wm * 128 + 64 + i * 16 + r16;
      av[i] = *(const bf16x8*)(as + ra * 32 + ((quad ^ (ra & 3)) << 3));
    }
    async_copy16(A  + ga + 128 * lda,     pa + 4096 + w * 512);
    async_copy16(BT + gb + 128 * (long)K, pb + 4096 + w * 512);
    asm volatile("" ::: "memory");
    __builtin_amdgcn_s_barrier();
    asm volatile("s_waitcnt lgkmcnt(0)" ::: "memory");
    __builtin_amdgcn_sched_barrier(0);
    __builtin_amdgcn_s_setprio(1);
#pragma unroll
    for (int i = 0; i < 4; i++)
#pragma unroll
      for (int j = 0; j < 4; j++)
        acc[i + 4][j] = __builtin_amdgcn_mfma_f32_16x16x32_bf16(av[i], bv[j], acc[i + 4][j], 0, 0, 0);
    __builtin_amdgcn_s_setprio(0);
    // Counted gate: outstanding = tiles t+1 (oldest 4), t+2, t+3 (12 total).
    // vmcnt(8) retires tile t+1 before next iteration reads it. Never 0.
    asm volatile("s_waitcnt vmcnt(8)" ::: "memory");
    __builtin_amdgcn_sched_barrier(0);
    asm volatile("" ::: "memory");
    __builtin_amdgcn_s_barrier();
  }

  // Bias into acc (C/D layout: col=lane&15, row=quad*4+reg, m89-verified).
#pragma unroll
  for (int j = 0; j < 4; j++) {
    const float bj = bias[col0 + wn * 64 + j * 16 + r16];
#pragma unroll
    for (int i = 0; i < 8; i++) {
      acc[i][j][0] += bj; acc[i][j][1] += bj;
      acc[i][j][2] += bj; acc[i][j][3] += bj;
    }
  }

  if constexpr (sizeof(OT) == 2) {
    // Repack epilogue: drain in-flight (garbage) stages, then reuse the
    // 128 KiB LDS as 8 wave regions [128][64] for 512B-contiguous stores.
    asm volatile("s_waitcnt vmcnt(0)" ::: "memory");
    __builtin_amdgcn_s_barrier();
    bf16_t* wreg = (w < 4) ? &As[w][0] : &Bs[w - 4][0];
#pragma unroll
    for (int i = 0; i < 8; i++)
#pragma unroll
      for (int j = 0; j < 4; j++)
#pragma unroll
        for (int r = 0; r < 4; r++)
          wreg[(i * 16 + quad * 4 + r) * 64 + j * 16 + r16] = (bf16_t)acc[i][j][r];
    asm volatile("s_waitcnt lgkmcnt(0)" ::: "memory");
    __builtin_amdgcn_s_barrier();
#pragma unroll
    for (int it = 0; it < 16; it++) {
      const int r = it * 16 + (tid >> 5);
      const int c = (tid & 31) * 8;
      const int ww = ((r >> 7) << 2) + (c >> 6);
      const bf16_t* src = ((ww < 4) ? &As[ww][0] : &Bs[ww - 4][0])
                          + (r & 127) * 64 + (c & 63);
      *(bf16x8*)((bf16_t*)C + (row0 + r) * ldc + col0 + c) = *(const bf16x8*)src;
    }
  } else {
    // fp32 output: 16-lane x 4B = 64B segments, no amplification; direct.
#pragma unroll
    for (int j = 0; j < 4; j++) {
      const long col = col0 + wn * 64 + j * 16 + r16;
#pragma unroll
      for (int i = 0; i < 8; i++) {
        const long row = row0 + wm * 128 + i * 16 + quad * 4;
#pragma unroll
        for (int r = 0; r < 4; r++)
          C[(row + r) * ldc + col] = (OT)acc[i][j][r];
      }
    }
  }
}

// ---------------------------------------------------------------------------
// Weight transpose+convert: in fp32 [R][C] -> out bf16 [C][R]. 32x32 tiles,
// block (32,8). out may point into a stacked [N_tot,K] buffer.
// ---------------------------------------------------------------------------
__global__ void transpose_f32_bf16(const float* __restrict__ in, bf16_t* __restrict__ out,
                                   int R, int C)
{
  __shared__ bf16_t tile[32][33];
  const int cb = blockIdx.x * 32, rb = blockIdx.y * 32;
  const int tx = threadIdx.x, ty = threadIdx.y;
#pragma unroll
  for (int i = 0; i < 32; i += 8)
    tile[ty + i][tx] = (bf16_t)in[(size_t)(rb + ty + i) * C + cb + tx];
  __syncthreads();
#pragma unroll
  for (int i = 0; i < 32; i += 8)
    out[(size_t)(cb + ty + i) * R + rb + tx] = tile[tx][ty + i];
}

// ---------------------------------------------------------------------------
// fp32 -> bf16 elementwise convert, 8 elems/thread. n % 8 == 0.
// ---------------------------------------------------------------------------
__global__ void cvt_f32_bf16(const float* __restrict__ in, bf16_t* __restrict__ out, long n)
{
  const long i = ((long)blockIdx.x * blockDim.x + threadIdx.x) * 8;
  if (i >= n) return;
  const float4 a = *(const float4*)(in + i);
  const float4 b = *(const float4*)(in + i + 4);
  bf16x8 o;
  o[0] = (bf16_t)a.x; o[1] = (bf16_t)a.y; o[2] = (bf16_t)a.z; o[3] = (bf16_t)a.w;
  o[4] = (bf16_t)b.x; o[5] = (bf16_t)b.y; o[6] = (bf16_t)b.z; o[7] = (bf16_t)b.w;
  *(bf16x8*)(out + i) = o;
}

// ---------------------------------------------------------------------------
// Concatenate biases for the merged GEMMs. 9216 threads.
// b1[2048]={bc,bckv,bkr} b2[3072]={bcq,bqr} b3[4096]={bck,bv}
// ---------------------------------------------------------------------------
__global__ void concat_bias(const float* bc, const float* bckv, const float* bkr,
                            const float* bcq, const float* bqr,
                            const float* bck, const float* bv,
                            float* b1, float* b2, float* b3)
{
  const int t = blockIdx.x * 256 + threadIdx.x;
  if (t < 2048) {
    b1[t] = (t < 512) ? bc[t] : (t < 1024) ? bckv[t - 512] : bkr[t - 1024];
  } else if (t < 5120) {
    const int u = t - 2048;
    b2[u] = (u < 2048) ? bcq[u] : bqr[u - 2048];
  } else if (t < 9216) {
    const int u = t - 5120;
    b3[u] = (u < 2048) ? bck[u] : bv[u - 2048];
  }
}

// ---------------------------------------------------------------------------
// Fused RoPE + per-token 16x16 head attention over the fused buffers.
// fused1[8192][2048]: cols 1024.. = kr(pre-rope)
// fused2[8192][3072]: cols 0..2047 = q (overwritten with output), 2048.. = qr
// fused3[8192][4096]: cols 0..2047 = k, 2048.. = v
// ---------------------------------------------------------------------------
__global__ __launch_bounds__(256) void attn_rope(
    const bf16_t* __restrict__ f1, bf16_t* f2, const bf16_t* __restrict__ f3)
{
  const int tok = blockIdx.x;
  const int pos = tok & 4095;   // position within sequence (S=4096)
  const int tid = threadIdx.x;

  __shared__ __align__(16) float qf[16 * 204];
  __shared__ __align__(16) float kf[16 * 204];
  __shared__ __align__(16) float vf[16 * 132];
  __shared__ float sc[256];

  const bf16_t* q  = f2 + (size_t)tok * 3072;
  const bf16_t* qr = q + 2048;
  const bf16_t* k  = f3 + (size_t)tok * 4096;
  const bf16_t* v  = k + 2048;
  const bf16_t* kr = f1 + (size_t)tok * 2048 + 1024;

  {
    const int h = tid >> 4, d = (tid & 15) * 8;
    bf16x8 xq = *(const bf16x8*)(q + tid * 8);
    bf16x8 xk = *(const bf16x8*)(k + tid * 8);
    bf16x8 xv = *(const bf16x8*)(v + tid * 8);
    float* qd = qf + h * 204 + d;
    float* kd = kf + h * 204 + d;
    float* vd = vf + h * 132 + d;
#pragma unroll
    for (int e = 0; e < 8; e++) {
      qd[e] = (float)xq[e];
      kd[e] = (float)xk[e];
      vd[e] = (float)xv[e];
    }
  }

  // RoPE: inv_freq[j] = 10000^(-j/32) = 2^(-j*log2(10000)/32)
  for (int p = tid; p < 512; p += 256) {
    const int h = p >> 5, j = p & 31;
    const float x1 = (float)qr[h * 64 + j];
    const float x2 = (float)qr[h * 64 + j + 32];
    const float y1 = (float)kr[h * 64 + j];
    const float y2 = (float)kr[h * 64 + j + 32];
    const float ang = (float)pos * exp2f((float)j * -0.41524101186092029f);
    float sn, cs;
    sincosf(ang, &sn, &cs);
    qf[h * 204 + 128 + j] = x1 * cs - x2 * sn;
    qf[h * 204 + 160 + j] = x2 * cs + x1 * sn;
    kf[h * 204 + 128 + j] = y1 * cs - y2 * sn;
    kf[h * 204 + 160 + j] = y2 * cs + y1 * sn;
  }
  __syncthreads();

  {
    const int i = tid >> 4, j = tid & 15;
    const float4* qrow = (const float4*)(qf + i * 204);
    const float4* krow = (const float4*)(kf + j * 204);
    float d0 = 0.f, d1 = 0.f, d2 = 0.f, d3 = 0.f;
#pragma unroll 8
    for (int dd = 0; dd < 48; dd++) {
      const float4 a = qrow[dd], b = krow[dd];
      d0 = fmaf(a.x, b.x, d0);
      d1 = fmaf(a.y, b.y, d1);
      d2 = fmaf(a.z, b.z, d2);
      d3 = fmaf(a.w, b.w, d3);
    }
    const float s = (d0 + d1 + d2 + d3) * 0.07216878364870323f; // 1/sqrt(192)
    float m = s;
    m = fmaxf(m, __shfl_xor(m, 1));
    m = fmaxf(m, __shfl_xor(m, 2));
    m = fmaxf(m, __shfl_xor(m, 4));
    m = fmaxf(m, __shfl_xor(m, 8));
    const float e = __expf(s - m);
    float sum = e;
    sum += __shfl_xor(sum, 1);
    sum += __shfl_xor(sum, 2);
    sum += __shfl_xor(sum, 4);
    sum += __shfl_xor(sum, 8);
    sc[i * 16 + j] = e / sum;
  }
  __syncthreads();

  {
    const int i = tid >> 4, dp = (tid & 15) * 8;
    float4 a0 = {0.f, 0.f, 0.f, 0.f}, a1 = {0.f, 0.f, 0.f, 0.f};
#pragma unroll
    for (int j = 0; j < 16; j++) {
      const float a = sc[i * 16 + j];
      const float4* vrow = (const float4*)(vf + j * 132 + dp);
      const float4 v0 = vrow[0], v1 = vrow[1];
      a0.x = fmaf(a, v0.x, a0.x);
      a0.y = fmaf(a, v0.y, a0.y);
      a0.z = fmaf(a, v0.z, a0.z);
      a0.w = fmaf(a, v0.w, a0.w);
      a1.x = fmaf(a, v1.x, a1.x);
      a1.y = fmaf(a, v1.y, a1.y);
      a1.z = fmaf(a, v1.z, a1.z);
      a1.w = fmaf(a, v1.w, a1.w);
    }
    bf16x8 o;
    o[0] = (bf16_t)a0.x; o[1] = (bf16_t)a0.y; o[2] = (bf16_t)a0.z; o[3] = (bf16_t)a0.w;
    o[4] = (bf16_t)a1.x; o[5] = (bf16_t)a1.y; o[6] = (bf16_t)a1.z; o[7] = (bf16_t)a1.w;
    // write over q columns of fused2 (this block read its own q above)
    *(bf16x8*)(f2 + (size_t)tok * 3072 + i * 128 + dp) = o;
  }
}

// ---------------------------------------------------------------------------
extern "C" void kernel_launch(void* const* d_in, const int* in_sizes, int n_in,
                              void* d_out, int out_size, void* d_ws, size_t ws_size,
                              hipStream_t stream)
{
  (void)in_sizes; (void)n_in; (void)out_size; (void)ws_size;

  const float* h_t  = (const float*)d_in[0];
  const float* Wc   = (const float*)d_in[1];
  const float* bc   = (const float*)d_in[2];
  const float* Wcq  = (const float*)d_in[3];
  const float* bcq  = (const float*)d_in[4];
  const float* Wqr  = (const float*)d_in[5];
  const float* bqr  = (const float*)d_in[6];
  const float* Wckv = (const float*)d_in[7];
  const float* bckv = (const float*)d_in[8];
  const float* Wck  = (const float*)d_in[9];
  const float* bck  = (const float*)d_in[10];
  const float* Wkr  = (const float*)d_in[11];
  const float* bkr  = (const float*)d_in[12];
  const float* Wv   = (const float*)d_in[13];
  const float* bv   = (const float*)d_in[14];
  const float* Wo   = (const float*)d_in[15];
  const float* bo   = (const float*)d_in[16];

  bf16_t* ws = (bf16_t*)d_ws;
  // ws layout (bf16 elems) — total 87,556,096 = 175,112,192 B (proven fit R4)
  bf16_t* W1T    = ws + 0;         // [2048,2048] rows: WcT 0-511, WckvT 512-1023, WkrT 1024-2047
  bf16_t* W2T    = ws + 4194304;   // [3072,512]  rows: WcqT 0-2047, WqrT 2048-3071
  bf16_t* W3T    = ws + 5767168;   // [4096,512]  rows: WckT 0-2047, WvT 2048-4095
  bf16_t* WoT    = ws + 7864320;   // [2048,2048]
  bf16_t* fused1 = ws + 12058624;  // [8192,2048] cq|ckv|kr_pre
  bf16_t* fused2 = ws + 28835840;  // [8192,3072] q|qr  (q cols become attn out)
  bf16_t* fused3 = ws + 54001664;  // [8192,4096] k|v

  // d_out as scratch until the final GEMM: bf16 h_t copy + concat'd biases
  bf16_t* hbf = (bf16_t*)d_out;                          // 16,777,216 elems (33.5 MB)
  float*  b1  = (float*)((char*)d_out + 33554432);       // 2048 f
  float*  b2  = b1 + 2048;                               // 3072 f
  float*  b3  = b2 + 3072;                               // 4096 f

  const dim3 tb(32, 8);
  transpose_f32_bf16<<<dim3(16, 64), tb, 0, stream>>>(Wc,   W1T,                2048, 512);
  transpose_f32_bf16<<<dim3(16, 64), tb, 0, stream>>>(Wckv, W1T + 512  * 2048,  2048, 512);
  transpose_f32_bf16<<<dim3(32, 64), tb, 0, stream>>>(Wkr,  W1T + 1024 * 2048,  2048, 1024);
  transpose_f32_bf16<<<dim3(64, 16), tb, 0, stream>>>(Wcq,  W2T,                512, 2048);
  transpose_f32_bf16<<<dim3(32, 16), tb, 0, stream>>>(Wqr,  W2T + 2048 * 512,   512, 1024);
  transpose_f32_bf16<<<dim3(64, 16), tb, 0, stream>>>(Wck,  W3T,                512, 2048);
  transpose_f32_bf16<<<dim3(64, 16), tb, 0, stream>>>(Wv,   W3T + 2048 * 512,   512, 2048);
  transpose_f32_bf16<<<dim3(64, 64), tb, 0, stream>>>(Wo,   WoT,                2048, 2048);
  concat_bias<<<36, 256, 0, stream>>>(bc, bckv, bkr, bcq, bqr, bck, bv, b1, b2, b3);
  cvt_f32_bf16<<<8192, 256, 0, stream>>>(h_t, hbf, 16777216L);

  // stage 1: [cq|ckv|kr_pre] = hbf @ [Wc|Wckv|Wkr]   M=8192 N=2048 K=2048
  gemm_bt256<bf16_t><<<dim3(8, 32), 512, 0, stream>>>(hbf, 2048, W1T, b1, fused1, 2048, 8192, 2048, 2048);
  // stage 2a: [q|qr] = cq @ [Wcq|Wqr]                M=8192 N=3072 K=512
  gemm_bt256<bf16_t><<<dim3(12, 32), 512, 0, stream>>>(fused1, 2048, W2T, b2, fused2, 3072, 8192, 3072, 512);
  // stage 2b: [k|v] = ckv @ [Wck|Wv]                 M=8192 N=4096 K=512
  gemm_bt256<bf16_t><<<dim3(16, 32), 512, 0, stream>>>(fused1 + 512, 2048, W3T, b3, fused3, 4096, 8192, 4096, 512);

  // fused rope + attention (output over q cols of fused2)
  attn_rope<<<8192, 256, 0, stream>>>(fused1, fused2, fused3);

  // output projection -> fp32 d_out                  M=8192 N=2048 K=2048
  gemm_bt256<float><<<dim3(8, 32), 512, 0, stream>>>(fused2, 3072, WoT, bo, (float*)d_out, 2048, 8192, 2048, 2048);
}